// Round 9
// baseline (256.527 us; speedup 1.0000x reference)
//
#include <hip/hip_runtime.h>
#include <stdint.h>

typedef unsigned short u16;
typedef unsigned int u32;

#define B_ 16
#define V_ 16
#define M_ 32
#define L_ 24
#define D_ 128
#define G_ 384   // 3*D
#define N_ 256   // B*V
#define NM_ 8192 // B*V*M
#define OUT_ 193

using bf16x8 = __attribute__((ext_vector_type(8))) __bf16;
using floatx4 = __attribute__((ext_vector_type(4))) float;

__device__ __forceinline__ float bf2f(u16 u) {
  u32 x = ((u32)u) << 16;
  return __builtin_bit_cast(float, x);
}
__device__ __forceinline__ u16 f2bf(float f) {
  u32 u = __builtin_bit_cast(u32, f);
  u = (u + 0x7FFFu + ((u >> 16) & 1u)) >> 16;
  return (u16)u;
}
__device__ __forceinline__ float sigm_(float x) {
  return __builtin_amdgcn_rcpf(1.0f + __expf(-x));
}
__device__ __forceinline__ float tanh_(float x) {
  float e = __expf(2.0f * x);
  return 1.0f - 2.0f * __builtin_amdgcn_rcpf(e + 1.0f);
}
__device__ __forceinline__ floatx4 mfma16(bf16x8 a, bf16x8 b, floatx4 c) {
  return __builtin_amdgcn_mfma_f32_16x16x32_bf16(a, b, c, 0, 0, 0);
}
// LDS-only barrier: drains lgkmcnt but leaves global loads (vmcnt) in flight.
__device__ __forceinline__ void lds_barrier() {
  asm volatile("s_waitcnt lgkmcnt(0)\n\ts_barrier" ::: "memory");
}

#define CONVB 4608  // 2*12*G*D / 256
#define VEB 128     // visit-embed blocks (2 visits each)
#define PEB 4096    // pair-embed blocks (2 rows each)

// ---------------- Stage 1: weight conv + visit embed + pair embed (fused) ----------------
__global__ __launch_bounds__(256) void k_stage1(
    const int* __restrict__ tc, const int* __restrict__ tp, const int* __restrict__ td,
    const int* __restrict__ tli, const int* __restrict__ tlv,
    const int* __restrict__ tii, const int* __restrict__ tiv,
    const float* __restrict__ ec, const float* __restrict__ ep, const float* __restrict__ ed,
    const float* __restrict__ eli, const float* __restrict__ elv,
    const float* __restrict__ eii, const float* __restrict__ eiv,
    const float* __restrict__ wv, const float* __restrict__ av,
    const float* __restrict__ iw, const float* __restrict__ ib,
    const float* __restrict__ mwih, const float* __restrict__ vwih,
    const float* __restrict__ mwhh, const float* __restrict__ vwhh,
    u16* __restrict__ wih_hi, u16* __restrict__ whh_hi,
    u16* __restrict__ ce_hi, u16* __restrict__ ce_lo,
    u16* __restrict__ vx_hi, u16* __restrict__ vx_lo,
    u16* __restrict__ mx_hi, u16* __restrict__ mx_lo) {
  int blk = blockIdx.x, tid = threadIdx.x;
  if (blk < CONVB) {
    const int SW = 12 * G_ * D_, S5 = 5 * G_ * D_;
    int i = blk * 256 + tid;
    if (i < SW) {
      float v = (i < S5) ? mwih[i] : vwih[i - S5];
      wih_hi[i] = f2bf(v);
    } else {
      int o = i - SW;
      float v = (o < S5) ? mwhh[o] : vwhh[o - S5];
      whh_hi[o] = f2bf(v);
    }
  } else if (blk < CONVB + VEB) {
    int n = (blk - CONVB) * 2 + (tid >> 7);
    int d = tid & 127;
    float a0 = 0.f, a1 = 0.f, a2 = 0.f;
#pragma unroll 4
    for (int l = 0; l < L_; l++) {
      a0 += ec[(size_t)tc[n * L_ + l] * D_ + d];
      a1 += ep[(size_t)tp[n * L_ + l] * D_ + d];
      a2 += ed[(size_t)td[n * L_ + l] * D_ + d];
    }
    size_t o0 = (size_t)n * D_ + d;
    u16 h;
    h = f2bf(a0); ce_hi[o0] = h;                   ce_lo[o0] = f2bf(a0 - bf2f(h));
    h = f2bf(a1); ce_hi[(size_t)N_ * D_ + o0] = h; ce_lo[(size_t)N_ * D_ + o0] = f2bf(a1 - bf2f(h));
    h = f2bf(a2); ce_hi[(size_t)2 * N_ * D_ + o0] = h; ce_lo[(size_t)2 * N_ * D_ + o0] = f2bf(a2 - bf2f(h));
    float wq = wv[n], aq = av[n];
    float v1 = wq * iw[d] + ib[d];
    float v2 = aq * iw[D_ + d] + ib[D_ + d];
    h = f2bf(v1); vx_hi[(size_t)5 * N_ * D_ + o0] = h; vx_lo[(size_t)5 * N_ * D_ + o0] = f2bf(v1 - bf2f(h));
    h = f2bf(v2); vx_hi[(size_t)6 * N_ * D_ + o0] = h; vx_lo[(size_t)6 * N_ * D_ + o0] = f2bf(v2 - bf2f(h));
  } else {
    int r = (blk - CONVB - VEB) * 2 + (tid >> 7);
    int d = tid & 127;
    float al = 0.f, ai = 0.f;
#pragma unroll 4
    for (int l = 0; l < L_; l++) {
      al += eli[(size_t)tli[r * L_ + l] * D_ + d] * elv[(size_t)tlv[r * L_ + l] * D_ + d];
      ai += eii[(size_t)tii[r * L_ + l] * D_ + d] * eiv[(size_t)tiv[r * L_ + l] * D_ + d];
    }
    size_t o = (size_t)r * D_ + d;
    u16 h;
    h = f2bf(al); mx_hi[o] = h;                    mx_lo[o] = f2bf(al - bf2f(h));
    h = f2bf(ai); mx_hi[(size_t)NM_ * D_ + o] = h; mx_lo[(size_t)NM_ * D_ + o] = f2bf(ai - bf2f(h));
  }
}

// ---------------- Fused GRU: xg GEMM folded into the recurrence ----------------
// Wave w owns cols 64j + dA (dA = 16w + mq), j=0..5 (j = gate*2 + dgroup).
// r/z gates (j=0..3): one chain seeded (bih+bhh), x-MFMAs + h-MFMAs merged.
// n gate (j=4,5): x-part (seed bih) and h-part (seed bhh) in SEPARATE accs —
// torch GRU applies r only to the h-part: n = tanh(xg_n + r*(gh_n)).
// Time-constant keys (MODE0 key<3) precompute their x-part once into registers.
template <int MODE, int TT>
__global__ __launch_bounds__(256, 1) void k_gru_f(
    int cpk,
    const u16* __restrict__ xc_hi, const u16* __restrict__ xc_lo,
    const u16* __restrict__ xt_hi, const u16* __restrict__ xt_lo,
    const u16* __restrict__ wih_all, const u16* __restrict__ whh_all,
    const float* __restrict__ bih_all, const float* __restrict__ bhh_all,
    u16* __restrict__ out_hi, u16* __restrict__ out_lo, float* __restrict__ out_f32) {
  int key = blockIdx.x / cpk;
  int chunk = blockIdx.x % cpk;
  int n0 = chunk * 16;
  const u16* wih = wih_all + (size_t)key * (G_ * D_);
  const u16* whh = whh_all + (size_t)key * (G_ * D_);
  const float* bih = bih_all + (size_t)key * G_;
  const float* bhh = bhh_all + (size_t)key * G_;

  __shared__ u16 hls[2][2][16 * 128];

  int tid = threadIdx.x;
  int w = tid >> 6, lane = tid & 63, mq = lane & 15, q = lane >> 4;
  int dA = 16 * w + mq;
  int ko = q * 8;

  bf16x8 wf[6][4], bw[6][4];
#pragma unroll
  for (int j = 0; j < 6; j++)
#pragma unroll
    for (int kk = 0; kk < 4; kk++) {
      size_t ro = (size_t)(64 * j + dA) * D_ + kk * 32 + ko;
      wf[j][kk] = *(const bf16x8*)(wih + ro);
      bw[j][kk] = *(const bf16x8*)(whh + ro);
    }

  floatx4 bmerge[4], bxn[2], bhn[2];
#pragma unroll
  for (int j = 0; j < 4; j++) {
    float b = bih[64 * j + dA] + bhh[64 * j + dA];
    bmerge[j] = {b, b, b, b};
  }
#pragma unroll
  for (int ab = 0; ab < 2; ab++) {
    float bx = bih[64 * (4 + ab) + dA];
    float bh = bhh[64 * (4 + ab) + dA];
    bxn[ab] = {bx, bx, bx, bx};
    bhn[ab] = {bh, bh, bh, bh};
  }

  const bool tv = (MODE == 1) || (key >= 3);
  const u16 *tb_hi, *tb_lo;
  if (MODE == 0) {
    if (key >= 3) {
      size_t o = ((size_t)(key - 3) * NM_ + (size_t)(n0 + mq) * M_) * D_ + ko;
      tb_hi = xt_hi + o; tb_lo = xt_lo + o;
    } else {
      size_t o = ((size_t)key * N_ + (n0 + mq)) * D_ + ko;
      tb_hi = xc_hi + o; tb_lo = xc_lo + o;
    }
  } else {
    size_t o = ((size_t)key * N_ + mq * 16) * D_ + ko;
    tb_hi = xc_hi + o; tb_lo = xc_lo + o;
  }

  floatx4 seedm[4], seedxn[2];
  bf16x8 xh[2][4], xl[2][4];
  if (!tv) {
#pragma unroll
    for (int kk = 0; kk < 4; kk++) {
      xh[0][kk] = *(const bf16x8*)(tb_hi + kk * 32);
      xl[0][kk] = *(const bf16x8*)(tb_lo + kk * 32);
    }
#pragma unroll
    for (int j = 0; j < 4; j++) {
      floatx4 a = bmerge[j];
#pragma unroll
      for (int kk = 0; kk < 4; kk++) {
        a = mfma16(xh[0][kk], wf[j][kk], a);
        a = mfma16(xl[0][kk], wf[j][kk], a);
      }
      seedm[j] = a;
    }
#pragma unroll
    for (int ab = 0; ab < 2; ab++) {
      floatx4 a = bxn[ab];
#pragma unroll
      for (int kk = 0; kk < 4; kk++) {
        a = mfma16(xh[0][kk], wf[4 + ab][kk], a);
        a = mfma16(xl[0][kk], wf[4 + ab][kk], a);
      }
      seedxn[ab] = a;
    }
  } else {
#pragma unroll
    for (int kk = 0; kk < 4; kk++) {
      xh[0][kk] = *(const bf16x8*)(tb_hi + kk * 32);
      xl[0][kk] = *(const bf16x8*)(tb_lo + kk * 32);
      xh[1][kk] = *(const bf16x8*)(tb_hi + D_ + kk * 32);
      xl[1][kk] = *(const bf16x8*)(tb_lo + D_ + kk * 32);
    }
  }

  float h_old[8];
#pragma unroll
  for (int k = 0; k < 8; k++) h_old[k] = 0.f;

#define GRU_STEP(P)                                                                  \
  {                                                                                  \
    int t = tb + (P);                                                                \
    floatx4 sm[4], sx[2], sh[2];                                                     \
    if (tv) {                                                                        \
      _Pragma("unroll") for (int j = 0; j < 4; j++) {                                \
        floatx4 a = bmerge[j];                                                       \
        _Pragma("unroll") for (int kk = 0; kk < 4; kk++) {                           \
          a = mfma16(xh[P][kk], wf[j][kk], a);                                       \
          a = mfma16(xl[P][kk], wf[j][kk], a);                                       \
        }                                                                            \
        sm[j] = a;                                                                   \
      }                                                                              \
      _Pragma("unroll") for (int ab = 0; ab < 2; ab++) {                             \
        floatx4 a = bxn[ab];                                                         \
        _Pragma("unroll") for (int kk = 0; kk < 4; kk++) {                           \
          a = mfma16(xh[P][kk], wf[4 + ab][kk], a);                                  \
          a = mfma16(xl[P][kk], wf[4 + ab][kk], a);                                  \
        }                                                                            \
        sx[ab] = a;                                                                  \
      }                                                                              \
      if (t + 2 < TT) {                                                              \
        size_t to = (size_t)(t + 2) * D_;                                            \
        _Pragma("unroll") for (int kk = 0; kk < 4; kk++) {                           \
          xh[P][kk] = *(const bf16x8*)(tb_hi + to + kk * 32);                        \
          xl[P][kk] = *(const bf16x8*)(tb_lo + to + kk * 32);                        \
        }                                                                            \
      }                                                                              \
    } else {                                                                         \
      _Pragma("unroll") for (int j = 0; j < 4; j++) sm[j] = seedm[j];                \
      _Pragma("unroll") for (int ab = 0; ab < 2; ab++) sx[ab] = seedxn[ab];          \
    }                                                                                \
    _Pragma("unroll") for (int ab = 0; ab < 2; ab++) sh[ab] = bhn[ab];               \
    if (t > 0) {                                                                     \
      const u16* hp0 = &hls[(t - 1) & 1][0][0];                                      \
      const u16* hp1 = &hls[(t - 1) & 1][1][0];                                      \
      bf16x8 ah[4], al[4];                                                           \
      _Pragma("unroll") for (int kk = 0; kk < 4; kk++) {                             \
        int off = mq * 128 + (((kk * 4 + q) ^ mq) * 8);                              \
        ah[kk] = *(const bf16x8*)(hp0 + off);                                        \
        al[kk] = *(const bf16x8*)(hp1 + off);                                        \
      }                                                                              \
      _Pragma("unroll") for (int j = 0; j < 4; j++) {                                \
        floatx4 a = sm[j];                                                           \
        _Pragma("unroll") for (int kk = 0; kk < 4; kk++) {                           \
          a = mfma16(ah[kk], bw[j][kk], a);                                          \
          a = mfma16(al[kk], bw[j][kk], a);                                          \
        }                                                                            \
        sm[j] = a;                                                                   \
      }                                                                              \
      _Pragma("unroll") for (int ab = 0; ab < 2; ab++) {                             \
        floatx4 a = sh[ab];                                                          \
        _Pragma("unroll") for (int kk = 0; kk < 4; kk++) {                           \
          a = mfma16(ah[kk], bw[4 + ab][kk], a);                                     \
          a = mfma16(al[kk], bw[4 + ab][kk], a);                                     \
        }                                                                            \
        sh[ab] = a;                                                                  \
      }                                                                              \
    }                                                                                \
    u16* wrh = &hls[t & 1][0][0];                                                    \
    u16* wrl = &hls[t & 1][1][0];                                                    \
    _Pragma("unroll") for (int i = 0; i < 4; i++) {                                  \
      int row = q * 4 + i;                                                           \
      _Pragma("unroll") for (int ab = 0; ab < 2; ab++) {                             \
        float r = sigm_(sm[0 + ab][i]);                                              \
        float z = sigm_(sm[2 + ab][i]);                                              \
        float nn = tanh_(sx[ab][i] + r * sh[ab][i]);                                 \
        float h2 = (1.0f - z) * nn + z * h_old[i * 2 + ab];                          \
        h_old[i * 2 + ab] = h2;                                                      \
        u32 ub = __builtin_bit_cast(u32, h2);                                        \
        u16 hb = (u16)(ub >> 16);                                                    \
        float rem = h2 - __builtin_bit_cast(float, ub & 0xFFFF0000u);                \
        u16 lb = f2bf(rem);                                                          \
        int d = dA + ab * 64;                                                        \
        if (t == TT - 1) {                                                           \
          if (MODE == 0) {                                                           \
            size_t o = ((size_t)key * N_ + n0 + row) * D_ + d;                       \
            out_hi[o] = hb;                                                          \
            out_lo[o] = lb;                                                          \
          } else {                                                                   \
            out_f32[((size_t)key * 16 + row) * D_ + d] = h2;                         \
          }                                                                          \
        } else {                                                                     \
          int idx = row * 128 + (((d >> 3) ^ row) * 8) + (d & 7);                    \
          wrh[idx] = hb;                                                             \
          wrl[idx] = lb;                                                             \
        }                                                                            \
      }                                                                              \
    }                                                                                \
    if (t + 1 < TT) lds_barrier();                                                   \
  }

#pragma unroll 1
  for (int tb = 0; tb < TT; tb += 2) {
    GRU_STEP(0)
    GRU_STEP(1)
  }
#undef GRU_STEP
}

// ---------------- ReLU + FC (parallel GEMV) ----------------
__global__ __launch_bounds__(256) void k_fc(
    const float* __restrict__ vis_h, const float* __restrict__ fc_w,
    const float* __restrict__ fc_b, float* __restrict__ out) {
  int b = blockIdx.x;
  int cg = blockIdx.y;
  int tid = threadIdx.x;
  int j = tid & 15, s = tid >> 4;
  int c = cg * 16 + j;
  bool cv = c < OUT_;

  __shared__ float hbuf[7 * D_];
  __shared__ float red[16][16];
  for (int i = tid; i < 7 * D_; i += 256) {
    float v = vis_h[((size_t)(i >> 7) * 16 + b) * D_ + (i & 127)];
    hbuf[i] = v > 0.f ? v : 0.f;
  }
  __syncthreads();

  float acc = 0.f;
  if (cv) {
    const float* wp = fc_w + (size_t)(s * 56) * OUT_ + c;
#pragma unroll 8
    for (int k = 0; k < 56; k++) acc += hbuf[s * 56 + k] * wp[(size_t)k * OUT_];
  }
  red[s][j] = acc;
  __syncthreads();
  if (s == 0 && cv) {
    float t = 0.f;
#pragma unroll
    for (int m = 0; m < 16; m++) t += red[m][j];
    out[(size_t)b * OUT_ + c] = t + fc_b[c];
  }
}

extern "C" void kernel_launch(void* const* d_in, const int* in_sizes, int n_in,
                              void* d_out, int out_size, void* d_ws, size_t ws_size,
                              hipStream_t stream) {
  (void)in_sizes; (void)n_in; (void)out_size; (void)ws_size;
  const int* tok_cond = (const int*)d_in[0];
  const int* tok_proc = (const int*)d_in[1];
  const int* tok_drug = (const int*)d_in[2];
  const int* tok_lab_item = (const int*)d_in[3];
  const int* tok_lab_value = (const int*)d_in[4];
  const int* tok_inj_item = (const int*)d_in[5];
  const int* tok_inj_value = (const int*)d_in[6];
  const float* weight = (const float*)d_in[7];
  const float* age = (const float*)d_in[8];
  const float* emb_cond = (const float*)d_in[9];
  const float* emb_proc = (const float*)d_in[10];
  const float* emb_drug = (const float*)d_in[11];
  const float* emb_lab_item = (const float*)d_in[12];
  const float* emb_lab_value = (const float*)d_in[13];
  const float* emb_inj_item = (const float*)d_in[14];
  const float* emb_inj_value = (const float*)d_in[15];
  const float* mgru_wih = (const float*)d_in[16];
  const float* mgru_whh = (const float*)d_in[17];
  const float* mgru_bih = (const float*)d_in[18];
  const float* mgru_bhh = (const float*)d_in[19];
  const float* vgru_wih = (const float*)d_in[20];
  const float* vgru_whh = (const float*)d_in[21];
  const float* vgru_bih = (const float*)d_in[22];
  const float* vgru_bhh = (const float*)d_in[23];
  const float* info_w = (const float*)d_in[24];
  const float* info_b = (const float*)d_in[25];
  const float* fc_w = (const float*)d_in[26];
  const float* fc_b = (const float*)d_in[27];

  char* p = (char*)d_ws;
  auto take = [&](size_t bytes) { char* r = p; p += (bytes + 255) & ~(size_t)255; return r; };
  u16* mx_hi = (u16*)take((size_t)2 * NM_ * D_ * 2);
  u16* mx_lo = (u16*)take((size_t)2 * NM_ * D_ * 2);
  u16* ce_hi = (u16*)take((size_t)3 * N_ * D_ * 2);
  u16* ce_lo = (u16*)take((size_t)3 * N_ * D_ * 2);
  u16* vx_hi = (u16*)take((size_t)7 * N_ * D_ * 2);
  u16* vx_lo = (u16*)take((size_t)7 * N_ * D_ * 2);
  float* vis_h = (float*)take((size_t)7 * 16 * D_ * 4);
  u16* wih_hi = (u16*)take((size_t)12 * G_ * D_ * 2);
  u16* whh_hi = (u16*)take((size_t)12 * G_ * D_ * 2);

  k_stage1<<<CONVB + VEB + PEB, 256, 0, stream>>>(
      tok_cond, tok_proc, tok_drug, tok_lab_item, tok_lab_value, tok_inj_item, tok_inj_value,
      emb_cond, emb_proc, emb_drug, emb_lab_item, emb_lab_value, emb_inj_item, emb_inj_value,
      weight, age, info_w, info_b, mgru_wih, vgru_wih, mgru_whh, vgru_whh,
      wih_hi, whh_hi, ce_hi, ce_lo, vx_hi, vx_lo, mx_hi, mx_lo);
  // monitor recurrence (fused xg): 5 keys x 16 chunks, T=32 -> writes vx keys 0..4
  k_gru_f<0, 32><<<80, 256, 0, stream>>>(16, ce_hi, ce_lo, mx_hi, mx_lo,
                                         wih_hi, whh_hi, mgru_bih, mgru_bhh,
                                         vx_hi, vx_lo, nullptr);
  // visit recurrence (fused xg): 7 keys, T=16 -> vis_h f32
  k_gru_f<1, 16><<<7, 256, 0, stream>>>(1, vx_hi, vx_lo, nullptr, nullptr,
                                        wih_hi + (size_t)5 * G_ * D_, whh_hi + (size_t)5 * G_ * D_,
                                        vgru_bih, vgru_bhh, nullptr, nullptr, vis_h);
  k_fc<<<dim3(B_, 13), 256, 0, stream>>>(vis_h, fc_w, fc_b, (float*)d_out);
}

// Round 10
// 222.036 us; speedup vs baseline: 1.1553x; 1.1553x over previous
//
#include <hip/hip_runtime.h>
#include <stdint.h>

typedef unsigned short u16;
typedef unsigned int u32;

#define B_ 16
#define V_ 16
#define M_ 32
#define L_ 24
#define D_ 128
#define G_ 384   // 3*D
#define N_ 256   // B*V
#define NM_ 8192 // B*V*M
#define OUT_ 193

using bf16x8 = __attribute__((ext_vector_type(8))) __bf16;
using floatx4 = __attribute__((ext_vector_type(4))) float;

__device__ __forceinline__ float bf2f(u16 u) {
  u32 x = ((u32)u) << 16;
  return __builtin_bit_cast(float, x);
}
__device__ __forceinline__ u16 f2bf(float f) {
  u32 u = __builtin_bit_cast(u32, f);
  u = (u + 0x7FFFu + ((u >> 16) & 1u)) >> 16;
  return (u16)u;
}
__device__ __forceinline__ float sigm_(float x) {
  return __builtin_amdgcn_rcpf(1.0f + __expf(-x));
}
__device__ __forceinline__ float tanh_(float x) {
  float e = __expf(2.0f * x);
  return 1.0f - 2.0f * __builtin_amdgcn_rcpf(e + 1.0f);
}
__device__ __forceinline__ floatx4 mfma16(bf16x8 a, bf16x8 b, floatx4 c) {
  return __builtin_amdgcn_mfma_f32_16x16x32_bf16(a, b, c, 0, 0, 0);
}
// LDS-only barrier: drains lgkmcnt but leaves global loads (vmcnt) in flight.
__device__ __forceinline__ void lds_barrier() {
  asm volatile("s_waitcnt lgkmcnt(0)\n\ts_barrier" ::: "memory");
}

#define CONVB 4608  // 2*12*G*D / 256
#define VEB 128     // visit-embed blocks (2 visits each)
#define PEB 4096    // pair-embed blocks (2 rows each)

// ---------------- Stage 1: weight conv + visit embed + pair embed (fused) ----------------
__global__ __launch_bounds__(256) void k_stage1(
    const int* __restrict__ tc, const int* __restrict__ tp, const int* __restrict__ td,
    const int* __restrict__ tli, const int* __restrict__ tlv,
    const int* __restrict__ tii, const int* __restrict__ tiv,
    const float* __restrict__ ec, const float* __restrict__ ep, const float* __restrict__ ed,
    const float* __restrict__ eli, const float* __restrict__ elv,
    const float* __restrict__ eii, const float* __restrict__ eiv,
    const float* __restrict__ wv, const float* __restrict__ av,
    const float* __restrict__ iw, const float* __restrict__ ib,
    const float* __restrict__ mwih, const float* __restrict__ vwih,
    const float* __restrict__ mwhh, const float* __restrict__ vwhh,
    u16* __restrict__ wih_hi, u16* __restrict__ whh_hi,
    u16* __restrict__ ce_hi, u16* __restrict__ ce_lo,
    u16* __restrict__ vx_hi, u16* __restrict__ vx_lo,
    u16* __restrict__ mx_hi, u16* __restrict__ mx_lo) {
  int blk = blockIdx.x, tid = threadIdx.x;
  if (blk < CONVB) {
    const int SW = 12 * G_ * D_, S5 = 5 * G_ * D_;
    int i = blk * 256 + tid;
    if (i < SW) {
      float v = (i < S5) ? mwih[i] : vwih[i - S5];
      wih_hi[i] = f2bf(v);
    } else {
      int o = i - SW;
      float v = (o < S5) ? mwhh[o] : vwhh[o - S5];
      whh_hi[o] = f2bf(v);
    }
  } else if (blk < CONVB + VEB) {
    int n = (blk - CONVB) * 2 + (tid >> 7);
    int d = tid & 127;
    float a0 = 0.f, a1 = 0.f, a2 = 0.f;
#pragma unroll 4
    for (int l = 0; l < L_; l++) {
      a0 += ec[(size_t)tc[n * L_ + l] * D_ + d];
      a1 += ep[(size_t)tp[n * L_ + l] * D_ + d];
      a2 += ed[(size_t)td[n * L_ + l] * D_ + d];
    }
    size_t o0 = (size_t)n * D_ + d;
    u16 h;
    h = f2bf(a0); ce_hi[o0] = h;                   ce_lo[o0] = f2bf(a0 - bf2f(h));
    h = f2bf(a1); ce_hi[(size_t)N_ * D_ + o0] = h; ce_lo[(size_t)N_ * D_ + o0] = f2bf(a1 - bf2f(h));
    h = f2bf(a2); ce_hi[(size_t)2 * N_ * D_ + o0] = h; ce_lo[(size_t)2 * N_ * D_ + o0] = f2bf(a2 - bf2f(h));
    float wq = wv[n], aq = av[n];
    float v1 = wq * iw[d] + ib[d];
    float v2 = aq * iw[D_ + d] + ib[D_ + d];
    h = f2bf(v1); vx_hi[(size_t)5 * N_ * D_ + o0] = h; vx_lo[(size_t)5 * N_ * D_ + o0] = f2bf(v1 - bf2f(h));
    h = f2bf(v2); vx_hi[(size_t)6 * N_ * D_ + o0] = h; vx_lo[(size_t)6 * N_ * D_ + o0] = f2bf(v2 - bf2f(h));
  } else {
    int r = (blk - CONVB - VEB) * 2 + (tid >> 7);
    int d = tid & 127;
    float al = 0.f, ai = 0.f;
#pragma unroll 4
    for (int l = 0; l < L_; l++) {
      al += eli[(size_t)tli[r * L_ + l] * D_ + d] * elv[(size_t)tlv[r * L_ + l] * D_ + d];
      ai += eii[(size_t)tii[r * L_ + l] * D_ + d] * eiv[(size_t)tiv[r * L_ + l] * D_ + d];
    }
    size_t o = (size_t)r * D_ + d;
    u16 h;
    h = f2bf(al); mx_hi[o] = h;                    mx_lo[o] = f2bf(al - bf2f(h));
    h = f2bf(ai); mx_hi[(size_t)NM_ * D_ + o] = h; mx_lo[(size_t)NM_ * D_ + o] = f2bf(ai - bf2f(h));
  }
}

// ---------------- xg = A @ W^T + bias (tiled: wave = 16 rows x 96 cols) ----------------
__global__ __launch_bounds__(256) void k_gemm_xg(
    const u16* __restrict__ A_hi, const u16* __restrict__ A_lo,
    const u16* __restrict__ W_hi,
    const float* __restrict__ bias,
    float* __restrict__ out, int A_ks, int W_ks, int b_ks, int o_ks) {
  int key = blockIdx.z;
  int w = threadIdx.x >> 6, lane = threadIdx.x & 63;
  int mq = lane & 15, q = lane >> 4;
  int row = blockIdx.x * 64 + w * 16;
  int cb = blockIdx.y * 96;

  const u16* Wk = W_hi + (size_t)key * W_ks;
  bf16x8 wf[6][4];
#pragma unroll
  for (int j = 0; j < 6; j++)
#pragma unroll
    for (int kk = 0; kk < 4; kk++)
      wf[j][kk] = *(const bf16x8*)(Wk + (size_t)(cb + j * 16 + mq) * D_ + kk * 32 + q * 8);

  const u16* Ah = A_hi + (size_t)key * A_ks + (size_t)(row + mq) * D_;
  const u16* Al = A_lo + (size_t)key * A_ks + (size_t)(row + mq) * D_;
  bf16x8 ah[4], al[4];
#pragma unroll
  for (int kk = 0; kk < 4; kk++) {
    ah[kk] = *(const bf16x8*)(Ah + kk * 32 + q * 8);
    al[kk] = *(const bf16x8*)(Al + kk * 32 + q * 8);
  }

  floatx4 acc[6];
#pragma unroll
  for (int j = 0; j < 6; j++) {
    float bv = bias[key * b_ks + cb + j * 16 + mq];
    acc[j] = {bv, bv, bv, bv};
  }
#pragma unroll
  for (int j = 0; j < 6; j++)
#pragma unroll
    for (int kk = 0; kk < 4; kk++) {
      acc[j] = mfma16(ah[kk], wf[j][kk], acc[j]);
      acc[j] = mfma16(al[kk], wf[j][kk], acc[j]);
    }

  float* op = out + (size_t)key * o_ks + (size_t)(row + q * 4) * G_ + cb + mq;
#pragma unroll
  for (int j = 0; j < 6; j++)
#pragma unroll
    for (int i = 0; i < 4; i++) op[(size_t)i * G_ + j * 16] = acc[j][i];
}

// ---------------- GRU recurrence: 8 waves, wave w owns gate-cols d in [16w,16w+16) ----------------
// Per wave: 3 col-tiles (one per gate r/z/n) -> 24 MFMAs/step, 12 xg f32 loads/step,
// 4 gate elements/lane. xg already holds x*wih + bih; h-chains seeded with bhh.
// h state: hi/lo bf16 LDS planes, fragment order, 16B-unit XOR swizzle, ping-pong.
template <int MODE, int TT>
__global__ __launch_bounds__(512, 1) void k_gru8(
    int cpk, const float* __restrict__ xg_a, const float* __restrict__ xg_b,
    const u16* __restrict__ whh_all, const float* __restrict__ bhh_all,
    u16* __restrict__ out_hi, u16* __restrict__ out_lo, float* __restrict__ out_f32) {
  int key = blockIdx.x / cpk;
  int chunk = blockIdx.x % cpk;
  int n0 = chunk * 16;
  const u16* whh = whh_all + (size_t)key * (G_ * D_);
  const float* bhh = bhh_all + (size_t)key * G_;

  __shared__ u16 hls[2][2][16 * 128];

  int tid = threadIdx.x;
  int w = tid >> 6, lane = tid & 63, mq = lane & 15, q = lane >> 4;
  int dA = (w << 4) + mq;

  // whh fragments: tile g covers cols g*128 + dA
  bf16x8 bw[3][4];
#pragma unroll
  for (int g = 0; g < 3; g++)
#pragma unroll
    for (int kk = 0; kk < 4; kk++)
      bw[g][kk] = *(const bf16x8*)(whh + (size_t)(g * 128 + dA) * D_ + kk * 32 + q * 8);

  floatx4 bseed[3];
#pragma unroll
  for (int g = 0; g < 3; g++) {
    float b = bhh[g * 128 + dA];
    bseed[g] = {b, b, b, b};
  }

  const float* xbase;
  size_t RS, TS;
  if (MODE == 0) {
    if (key < 3) { xbase = xg_a + ((size_t)key * N_ + n0) * G_; RS = G_; TS = 0; }
    else { xbase = xg_b + ((size_t)(key - 3) * NM_ + (size_t)n0 * M_) * G_; RS = (size_t)M_ * G_; TS = G_; }
  } else {
    xbase = xg_a + (size_t)key * N_ * G_; RS = (size_t)16 * G_; TS = G_;
  }
  const float* rowp[4];
#pragma unroll
  for (int i = 0; i < 4; i++) rowp[i] = xbase + (size_t)(q * 4 + i) * RS + dA;

  // 4 statically-indexed xg streams; stream P holds time t with t%4==P (depth-3 prefetch).
  float xs[4][12];
#pragma unroll
  for (int s = 0; s < 3; s++) {
    int ts = s < TT ? s : TT - 1;
#pragma unroll
    for (int i = 0; i < 4; i++)
#pragma unroll
      for (int g = 0; g < 3; g++)
        xs[s][i * 3 + g] = rowp[i][(size_t)ts * TS + g * 128];
  }

  float h_old[4];
#pragma unroll
  for (int k = 0; k < 4; k++) h_old[k] = 0.f;

#define GRU_STEP(P)                                                                        \
  {                                                                                        \
    int t = tb + (P);                                                                      \
    {                                                                                      \
      int tpf = t + 3 < TT ? t + 3 : TT - 1;                                               \
      size_t to = (size_t)tpf * TS;                                                        \
      _Pragma("unroll") for (int i = 0; i < 4; i++)                                        \
          _Pragma("unroll") for (int g = 0; g < 3; g++)                                    \
              xs[((P) + 3) & 3][i * 3 + g] = rowp[i][to + g * 128];                        \
    }                                                                                      \
    floatx4 acc[3];                                                                        \
    if (t > 0) {                                                                           \
      const u16* hp0 = &hls[(t - 1) & 1][0][0];                                            \
      const u16* hp1 = &hls[(t - 1) & 1][1][0];                                            \
      bf16x8 ah[4], al[4];                                                                 \
      _Pragma("unroll") for (int kk = 0; kk < 4; kk++) {                                   \
        int off = mq * 128 + (((kk * 4 + q) ^ mq) * 8);                                    \
        ah[kk] = *(const bf16x8*)(hp0 + off);                                              \
        al[kk] = *(const bf16x8*)(hp1 + off);                                              \
      }                                                                                    \
      _Pragma("unroll") for (int g = 0; g < 3; g++) {                                      \
        floatx4 a = mfma16(ah[0], bw[g][0], bseed[g]);                                     \
        a = mfma16(al[0], bw[g][0], a);                                                    \
        a = mfma16(ah[1], bw[g][1], a);                                                    \
        a = mfma16(al[1], bw[g][1], a);                                                    \
        a = mfma16(ah[2], bw[g][2], a);                                                    \
        a = mfma16(al[2], bw[g][2], a);                                                    \
        a = mfma16(ah[3], bw[g][3], a);                                                    \
        acc[g] = mfma16(al[3], bw[g][3], a);                                               \
      }                                                                                    \
    } else {                                                                               \
      _Pragma("unroll") for (int g = 0; g < 3; g++) acc[g] = bseed[g];                     \
    }                                                                                      \
    u16* wrh = &hls[t & 1][0][0];                                                          \
    u16* wrl = &hls[t & 1][1][0];                                                          \
    _Pragma("unroll") for (int i = 0; i < 4; i++) {                                        \
      int row = q * 4 + i;                                                                 \
      float r = sigm_(xs[P][i * 3 + 0] + acc[0][i]);                                       \
      float z = sigm_(xs[P][i * 3 + 1] + acc[1][i]);                                       \
      float nn = tanh_(xs[P][i * 3 + 2] + r * acc[2][i]);                                  \
      float h2 = (1.0f - z) * nn + z * h_old[i];                                           \
      h_old[i] = h2;                                                                       \
      u32 ub = __builtin_bit_cast(u32, h2);                                                \
      u16 hb = (u16)(ub >> 16);                                                            \
      float rem = h2 - __builtin_bit_cast(float, ub & 0xFFFF0000u);                        \
      u16 lb = f2bf(rem);                                                                  \
      if (t == TT - 1) {                                                                   \
        if (MODE == 0) {                                                                   \
          size_t o = ((size_t)key * N_ + n0 + row) * D_ + dA;                              \
          out_hi[o] = hb;                                                                  \
          out_lo[o] = lb;                                                                  \
        } else {                                                                           \
          out_f32[((size_t)key * 16 + row) * D_ + dA] = h2;                                \
        }                                                                                  \
      } else {                                                                             \
        int idx = row * 128 + (((dA >> 3) ^ row) * 8) + (dA & 7);                          \
        wrh[idx] = hb;                                                                     \
        wrl[idx] = lb;                                                                     \
      }                                                                                    \
    }                                                                                      \
    if (t + 1 < TT) lds_barrier();                                                         \
  }

#pragma unroll 1
  for (int tb = 0; tb < TT; tb += 4) {
    GRU_STEP(0)
    GRU_STEP(1)
    GRU_STEP(2)
    GRU_STEP(3)
  }
#undef GRU_STEP
}

// ---------------- ReLU + FC (parallel GEMV) ----------------
__global__ __launch_bounds__(256) void k_fc(
    const float* __restrict__ vis_h, const float* __restrict__ fc_w,
    const float* __restrict__ fc_b, float* __restrict__ out) {
  int b = blockIdx.x;
  int cg = blockIdx.y;
  int tid = threadIdx.x;
  int j = tid & 15, s = tid >> 4;
  int c = cg * 16 + j;
  bool cv = c < OUT_;

  __shared__ float hbuf[7 * D_];
  __shared__ float red[16][16];
  for (int i = tid; i < 7 * D_; i += 256) {
    float v = vis_h[((size_t)(i >> 7) * 16 + b) * D_ + (i & 127)];
    hbuf[i] = v > 0.f ? v : 0.f;
  }
  __syncthreads();

  float acc = 0.f;
  if (cv) {
    const float* wp = fc_w + (size_t)(s * 56) * OUT_ + c;
#pragma unroll 8
    for (int k = 0; k < 56; k++) acc += hbuf[s * 56 + k] * wp[(size_t)k * OUT_];
  }
  red[s][j] = acc;
  __syncthreads();
  if (s == 0 && cv) {
    float t = 0.f;
#pragma unroll
    for (int m = 0; m < 16; m++) t += red[m][j];
    out[(size_t)b * OUT_ + c] = t + fc_b[c];
  }
}

extern "C" void kernel_launch(void* const* d_in, const int* in_sizes, int n_in,
                              void* d_out, int out_size, void* d_ws, size_t ws_size,
                              hipStream_t stream) {
  (void)in_sizes; (void)n_in; (void)out_size; (void)ws_size;
  const int* tok_cond = (const int*)d_in[0];
  const int* tok_proc = (const int*)d_in[1];
  const int* tok_drug = (const int*)d_in[2];
  const int* tok_lab_item = (const int*)d_in[3];
  const int* tok_lab_value = (const int*)d_in[4];
  const int* tok_inj_item = (const int*)d_in[5];
  const int* tok_inj_value = (const int*)d_in[6];
  const float* weight = (const float*)d_in[7];
  const float* age = (const float*)d_in[8];
  const float* emb_cond = (const float*)d_in[9];
  const float* emb_proc = (const float*)d_in[10];
  const float* emb_drug = (const float*)d_in[11];
  const float* emb_lab_item = (const float*)d_in[12];
  const float* emb_lab_value = (const float*)d_in[13];
  const float* emb_inj_item = (const float*)d_in[14];
  const float* emb_inj_value = (const float*)d_in[15];
  const float* mgru_wih = (const float*)d_in[16];
  const float* mgru_whh = (const float*)d_in[17];
  const float* mgru_bih = (const float*)d_in[18];
  const float* mgru_bhh = (const float*)d_in[19];
  const float* vgru_wih = (const float*)d_in[20];
  const float* vgru_whh = (const float*)d_in[21];
  const float* vgru_bih = (const float*)d_in[22];
  const float* vgru_bhh = (const float*)d_in[23];
  const float* info_w = (const float*)d_in[24];
  const float* info_b = (const float*)d_in[25];
  const float* fc_w = (const float*)d_in[26];
  const float* fc_b = (const float*)d_in[27];

  char* p = (char*)d_ws;
  auto take = [&](size_t bytes) { char* r = p; p += (bytes + 255) & ~(size_t)255; return r; };
  u16* mx_hi = (u16*)take((size_t)2 * NM_ * D_ * 2);
  u16* mx_lo = (u16*)take((size_t)2 * NM_ * D_ * 2);
  u16* ce_hi = (u16*)take((size_t)3 * N_ * D_ * 2);
  u16* ce_lo = (u16*)take((size_t)3 * N_ * D_ * 2);
  u16* vx_hi = (u16*)take((size_t)7 * N_ * D_ * 2);
  u16* vx_lo = (u16*)take((size_t)7 * N_ * D_ * 2);
  float* xg_mon = (float*)take((size_t)2 * NM_ * G_ * 4);
  float* xg_c = (float*)take((size_t)3 * N_ * G_ * 4);
  float* xg_v = (float*)take((size_t)7 * N_ * G_ * 4);
  float* vis_h = (float*)take((size_t)7 * 16 * D_ * 4);
  u16* wih_hi = (u16*)take((size_t)12 * G_ * D_ * 2);
  u16* whh_hi = (u16*)take((size_t)12 * G_ * D_ * 2);

  k_stage1<<<CONVB + VEB + PEB, 256, 0, stream>>>(
      tok_cond, tok_proc, tok_drug, tok_lab_item, tok_lab_value, tok_inj_item, tok_inj_value,
      emb_cond, emb_proc, emb_drug, emb_lab_item, emb_lab_value, emb_inj_item, emb_inj_value,
      weight, age, info_w, info_b, mgru_wih, vgru_wih, mgru_whh, vgru_whh,
      wih_hi, whh_hi, ce_hi, ce_lo, vx_hi, vx_lo, mx_hi, mx_lo);
  // xg for lab/inj monitor keys (3,4): rows = 8192 each
  k_gemm_xg<<<dim3(NM_ / 64, 4, 2), 256, 0, stream>>>(
      mx_hi, mx_lo, wih_hi + (size_t)3 * G_ * D_,
      mgru_bih + 3 * G_, xg_mon, NM_ * D_, G_ * D_, G_, NM_ * G_);
  // xg for time-constant monitor keys (0..2): rows = 256 each
  k_gemm_xg<<<dim3(N_ / 64, 4, 3), 256, 0, stream>>>(
      ce_hi, ce_lo, wih_hi, mgru_bih, xg_c, N_ * D_, G_ * D_, G_, N_ * G_);
  // monitor recurrence: 5 keys x 16 chunks, T=32 -> writes vx keys 0..4
  k_gru8<0, 32><<<80, 512, 0, stream>>>(16, xg_c, xg_mon, whh_hi, mgru_bhh,
                                        vx_hi, vx_lo, nullptr);
  // xg for visit keys (0..6): rows = 256 each
  k_gemm_xg<<<dim3(N_ / 64, 4, 7), 256, 0, stream>>>(
      vx_hi, vx_lo, wih_hi + (size_t)5 * G_ * D_,
      vgru_bih, xg_v, N_ * D_, G_ * D_, G_, N_ * G_);
  // visit recurrence: 7 keys, T=16 -> vis_h f32
  k_gru8<1, 16><<<7, 512, 0, stream>>>(1, xg_v, nullptr, whh_hi + (size_t)5 * G_ * D_, vgru_bhh,
                                       nullptr, nullptr, vis_h);
  k_fc<<<dim3(B_, 13), 256, 0, stream>>>(vis_h, fc_w, fc_b, (float*)d_out);
}